// Round 13
// baseline (582.034 us; speedup 1.0000x reference)
//
#include <hip/hip_runtime.h>
#include <math.h>

#define TLEN 1024
#define BSZ  16
#define DIN  128
#define KP   16
#define NEIG 64
#define MOUT 128
#define CHUNK_T 256
#define NCHUNK  4

// ws layout (float units)
static constexpr size_t XCQ_OFF = 0;        // 262144: xc f32 [t][b][k]
static constexpr size_t LAM_OFF = 262144;   // 2048:  lambda c32
static constexpr size_t BQ_OFF  = 264192;   // 2048:  B' c32
static constexpr size_t CP_OFF  = 266240;   // 262144: Cp c32 [(k*64+j)*128+m]
static constexpr size_t ST_OFF  = 528384;   // 65536: scan state
static constexpr size_t S2_OFF  = 593920;   // 8388608: s2 chunk [4096][1024] float2
static constexpr size_t P_OFF   = 8982528;  // 8388608: k-split partials [16][4096][128]
// total: 17,371,136 floats = 69.48 MB (proven usable)

__device__ __forceinline__ float f32cos(float x) { return (float)cos((double)x); }
__device__ __forceinline__ float f32sin(float x) { return (float)sin((double)x); }

__device__ __forceinline__ float2 cdiv32(float ar, float ai, float cr, float ci) {
  float2 o;
  if (fabsf(ci) <= fabsf(cr)) {
    float rat = __fdiv_rn(ci, cr);
    float scl = __fdiv_rn(1.0f, __fadd_rn(cr, __fmul_rn(ci, rat)));
    o.x = __fmul_rn(__fadd_rn(ar, __fmul_rn(ai, rat)), scl);
    o.y = __fmul_rn(__fsub_rn(ai, __fmul_rn(ar, rat)), scl);
  } else {
    float rat = __fdiv_rn(cr, ci);
    float scl = __fdiv_rn(1.0f, __fadd_rn(ci, __fmul_rn(cr, rat)));
    o.x = __fmul_rn(__fadd_rn(__fmul_rn(ar, rat), ai), scl);
    o.y = __fmul_rn(__fsub_rn(__fmul_rn(ai, rat), ar), scl);
  }
  return o;
}

// ---------------------------------------------------------------------------
__global__ __launch_bounds__(256) void k_lam_B(const float* __restrict__ theta,
                        float2* __restrict__ lam, float2* __restrict__ Bq) {
  __shared__ float2 terms[4][64];
  int wid  = threadIdx.x >> 6;
  int lane = threadIdx.x & 63;
  int idx = blockIdx.x * 4 + wid;
  int k = idx >> 6, j = idx & 63;
  float thj = (j < 32) ? theta[k * 32 + j] : -theta[k * 32 + (j - 32)];
  float ljr = f32cos(thj), lji = f32sin(thj);
  float2 tm = make_float2(0.f, 0.f);
  if (lane != j) {
    int i = lane;
    float thi = (i < 32) ? theta[k * 32 + i] : -theta[k * 32 + (i - 32)];
    float lir = f32cos(thi), lii = f32sin(thi);
    float2 r = cdiv32(lir, lii, ljr, lji);
    float tr = __fsub_rn(1.0f, r.x);
    float ti = __fsub_rn(0.0f, r.y);
    double h = sqrt((double)tr * tr + (double)ti * ti);
    tm.x = (float)log(h);
    tm.y = (float)atan2((double)ti, (double)tr);
  }
  terms[wid][lane] = tm;
  __syncthreads();
  if (lane == 0) {
    lam[idx] = make_float2(ljr, lji);
    float sr = 0.f, si = 0.f;
    for (int i = 0; i < NEIG; ++i) {
      sr = __fadd_rn(sr, terms[wid][i].x);
      si = __fadd_rn(si, terms[wid][i].y);
    }
    float er = (float)exp((double)(-sr));
    float cc = f32cos(-si), ss = f32sin(-si);
    Bq[idx] = make_float2(__fmul_rn(er, cc), __fmul_rn(er, ss));
  }
}

// ---------------------------------------------------------------------------
__global__ __launch_bounds__(128) void k_Cp(const float* __restrict__ theta,
                     const float* __restrict__ C, float2* __restrict__ Cp) {
  __shared__ float2 sU[64];
  __shared__ float  sC[128][65];
  int tid = threadIdx.x;
  int kj = blockIdx.x;
  int j = kj & 63, k = kj >> 6;
  float lnim = (j < 32) ? theta[k * 32 + j] : -theta[k * 32 + (j - 32)];
  if (tid < 64) {
    int i = tid;
    float p = (float)(63 - i);
    float ph = -__fmul_rn(p, lnim);
    sU[i] = make_float2(f32cos(ph), f32sin(ph));
  }
  const float* Ck = C + ((size_t)k << 13);
  for (int e = tid; e < 128 * 64; e += 128) {
    sC[e >> 6][e & 63] = Ck[e];
  }
  __syncthreads();
  int m = tid;
  float ar = 0.f, ai = 0.f;
  #pragma unroll 8
  for (int i = 0; i < NEIG; ++i) {
    float Cv = sC[m][i];
    float2 U = sU[i];
    ar = __fadd_rn(ar, __fmul_rn(Cv, U.x));
    ai = __fadd_rn(ai, __fmul_rn(Cv, U.y));
  }
  Cp[(size_t)(k * 64 + j) * MOUT + m] = make_float2(ar, ai);
}

// ---------------------------------------------------------------------------
__global__ __launch_bounds__(256) void k_xc(const float* __restrict__ x,
                     const float* __restrict__ R, float* __restrict__ xcq) {
  __shared__ float sX[16][132];
  __shared__ float sR[128][16];
  int tid = threadIdx.x;
  int rBase = blockIdx.x * 16;
  for (int e = tid; e < DIN * KP; e += 256) sR[e >> 4][e & 15] = R[e];
  #pragma unroll
  for (int it = 0; it < 2; ++it) {
    int e = tid + it * 256;
    int row = e >> 5, q = e & 31;
    int g = rBase + row;
    int t = g >> 4, b = g & 15;
    float4 v = *(const float4*)(x + ((size_t)b * TLEN + t) * DIN + q * 4);
    *(float4*)&sX[row][q * 4] = v;
  }
  __syncthreads();
  int r = tid >> 4, k = tid & 15;
  double acc = 0.0;
  #pragma unroll 16
  for (int d = 0; d < DIN; ++d)
    acc = fma((double)sX[r][d], (double)sR[d][k], acc);
  xcq[(size_t)(rBase + r) * KP + k] = (float)acc;
}

// ---------------------------------------------------------------------------
// Scan v7: ILP-2 — lane j (j<32) carries modes j and j+32 (independent
// recurrences) interleaved in registers; batch-8 alpha pipeline as v6.
// Per-mode op sequence identical to rounds 4-12 -> bit-identical output.
__global__ __launch_bounds__(64) void k_scan(const float2* __restrict__ lam,
                        const float2* __restrict__ Bq,
                        const float* __restrict__ xcq,
                        float2* __restrict__ S2,
                        float* __restrict__ state, int c) {
  __shared__ float sXq[CHUNK_T];
  int j = threadIdx.x;
  int chain = blockIdx.x;              // b*16 + k
  int b = chain >> 4, k = chain & 15;
  int t0 = c * CHUNK_T;
  int tlBeg = (c == 0) ? 1 : 0;
  for (int i = j; i < CHUNK_T; i += 64) {
    int g = t0 + tlBeg - 1 + i;
    sXq[i] = xcq[(size_t)g * (BSZ * KP) + b * KP + k];
  }
  __syncthreads();
  if (j >= 32) return;                 // single wave; no further barriers
  int m0 = k * 64 + j, m1 = m0 + 32;
  float lr0 = lam[m0].x, li0 = lam[m0].y, lr1 = lam[m1].x, li1 = lam[m1].y;
  float Br0 = Bq[m0].x,  Bi0 = Bq[m0].y,  Br1 = Bq[m1].x,  Bi1 = Bq[m1].y;
  float* st0 = state + (size_t)(chain * 64 + j) * 4;
  float* st1 = state + (size_t)(chain * 64 + j + 32) * 4;
  float s1r0, s1i0, s2r0, s2i0, s1r1, s1i1, s2r1, s2i1;
  if (c == 0) {
    s1r0 = s1i0 = s2r0 = s2i0 = 0.f;
    s1r1 = s1i1 = s2r1 = s2i1 = 0.f;
    S2[(size_t)(0 * BSZ + b) * 1024 + m0] = make_float2(0.f, 0.f);
    S2[(size_t)(0 * BSZ + b) * 1024 + m1] = make_float2(0.f, 0.f);
  } else {
    s1r0 = st0[0]; s1i0 = st0[1]; s2r0 = st0[2]; s2i0 = st0[3];
    s1r1 = st1[0]; s1i1 = st1[1]; s2r1 = st1[2]; s2i1 = st1[3];
  }

  int tl = tlBeg;
  for (; tl + 8 <= CHUNK_T; tl += 8) {
    float als0[8], als1[8];
    #pragma unroll
    for (int u = 0; u < 8; ++u) {
      float xq = sXq[tl - tlBeg + u];
      // mode j
      float lsr0 = __fsub_rn(__fmul_rn(lr0, s1r0), __fmul_rn(li0, s1i0));
      float lsi0 = __fadd_rn(__fmul_rn(lr0, s1i0), __fmul_rn(li0, s1r0));
      float h0 = (float)sqrt((double)lsr0 * lsr0 + (double)lsi0 * lsi0);
      als0[u] = __fdiv_rn(1.0f, __fsqrt_rn(__fadd_rn(1.0f, __fmul_rn(h0, h0))));
      float bxr0 = __fmul_rn(xq, Br0), bxi0 = __fmul_rn(xq, Bi0);
      s1r0 = __fadd_rn(lsr0, bxr0);
      s1i0 = __fadd_rn(lsi0, bxi0);
      // mode j+32 (independent — fills the stall slots)
      float lsr1 = __fsub_rn(__fmul_rn(lr1, s1r1), __fmul_rn(li1, s1i1));
      float lsi1 = __fadd_rn(__fmul_rn(lr1, s1i1), __fmul_rn(li1, s1r1));
      float h1 = (float)sqrt((double)lsr1 * lsr1 + (double)lsi1 * lsi1);
      als1[u] = __fdiv_rn(1.0f, __fsqrt_rn(__fadd_rn(1.0f, __fmul_rn(h1, h1))));
      float bxr1 = __fmul_rn(xq, Br1), bxi1 = __fmul_rn(xq, Bi1);
      s1r1 = __fadd_rn(lsr1, bxr1);
      s1i1 = __fadd_rn(lsi1, bxi1);
    }
    #pragma unroll
    for (int u = 0; u < 8; ++u) {
      float xq = sXq[tl - tlBeg + u];
      size_t rowOff = (size_t)((tl + u) * BSZ + b) * 1024;
      float bxr0 = __fmul_rn(xq, Br0), bxi0 = __fmul_rn(xq, Bi0);
      float a2r0 = __fmul_rn(als0[u], lr0), a2i0 = __fmul_rn(als0[u], li0);
      float t2r0 = __fsub_rn(__fmul_rn(a2r0, s2r0), __fmul_rn(a2i0, s2i0));
      float t2i0 = __fadd_rn(__fmul_rn(a2r0, s2i0), __fmul_rn(a2i0, s2r0));
      s2r0 = __fadd_rn(t2r0, bxr0);
      s2i0 = __fadd_rn(t2i0, bxi0);
      S2[rowOff + m0] = make_float2(s2r0, s2i0);
      float bxr1 = __fmul_rn(xq, Br1), bxi1 = __fmul_rn(xq, Bi1);
      float a2r1 = __fmul_rn(als1[u], lr1), a2i1 = __fmul_rn(als1[u], li1);
      float t2r1 = __fsub_rn(__fmul_rn(a2r1, s2r1), __fmul_rn(a2i1, s2i1));
      float t2i1 = __fadd_rn(__fmul_rn(a2r1, s2i1), __fmul_rn(a2i1, s2r1));
      s2r1 = __fadd_rn(t2r1, bxr1);
      s2i1 = __fadd_rn(t2i1, bxi1);
      S2[rowOff + m1] = make_float2(s2r1, s2i1);
    }
  }
  for (; tl < CHUNK_T; ++tl) {
    float xq = sXq[tl - tlBeg];
    size_t rowOff = (size_t)(tl * BSZ + b) * 1024;
    {
      float lsr = __fsub_rn(__fmul_rn(lr0, s1r0), __fmul_rn(li0, s1i0));
      float lsi = __fadd_rn(__fmul_rn(lr0, s1i0), __fmul_rn(li0, s1r0));
      float h  = (float)sqrt((double)lsr * lsr + (double)lsi * lsi);
      float al = __fdiv_rn(1.0f, __fsqrt_rn(__fadd_rn(1.0f, __fmul_rn(h, h))));
      float bxr = __fmul_rn(xq, Br0), bxi = __fmul_rn(xq, Bi0);
      float a2r = __fmul_rn(al, lr0), a2i = __fmul_rn(al, li0);
      float t2r = __fsub_rn(__fmul_rn(a2r, s2r0), __fmul_rn(a2i, s2i0));
      float t2i = __fadd_rn(__fmul_rn(a2r, s2i0), __fmul_rn(a2i, s2r0));
      s2r0 = __fadd_rn(t2r, bxr);
      s2i0 = __fadd_rn(t2i, bxi);
      s1r0 = __fadd_rn(lsr, bxr);
      s1i0 = __fadd_rn(lsi, bxi);
      S2[rowOff + m0] = make_float2(s2r0, s2i0);
    }
    {
      float lsr = __fsub_rn(__fmul_rn(lr1, s1r1), __fmul_rn(li1, s1i1));
      float lsi = __fadd_rn(__fmul_rn(lr1, s1i1), __fmul_rn(li1, s1r1));
      float h  = (float)sqrt((double)lsr * lsr + (double)lsi * lsi);
      float al = __fdiv_rn(1.0f, __fsqrt_rn(__fadd_rn(1.0f, __fmul_rn(h, h))));
      float bxr = __fmul_rn(xq, Br1), bxi = __fmul_rn(xq, Bi1);
      float a2r = __fmul_rn(al, lr1), a2i = __fmul_rn(al, li1);
      float t2r = __fsub_rn(__fmul_rn(a2r, s2r1), __fmul_rn(a2i, s2i1));
      float t2i = __fadd_rn(__fmul_rn(a2r, s2i1), __fmul_rn(a2i, s2r1));
      s2r1 = __fadd_rn(t2r, bxr);
      s2i1 = __fadd_rn(t2i, bxi);
      s1r1 = __fadd_rn(lsr, bxr);
      s1i1 = __fadd_rn(lsi, bxi);
      S2[rowOff + m1] = make_float2(s2r1, s2i1);
    }
  }
  st0[0] = s1r0; st0[1] = s1i0; st0[2] = s2r0; st0[3] = s2i0;
  st1[0] = s1r1; st1[1] = s1i1; st1[2] = s2r1; st1[3] = s2i1;
}

// ---------------------------------------------------------------------------
// k_y v10: R9's exact scalar inner loop (proven 52.4 us), but 4 n-phases of
// 16 -> LDS 32.9 KB -> 4 blocks/CU at natural VGPR (NO forced min-waves; R11's
// spill came from __launch_bounds__(256,4)). Arithmetic identical to R4-12.
__global__ __launch_bounds__(256) void k_y(const float2* __restrict__ S2,
                     const float2* __restrict__ Cp, const float* __restrict__ xcq,
                     const float* __restrict__ D, const float* __restrict__ Dov,
                     float* __restrict__ P, int c) {
  __shared__ float2 sS2t[16][129];   // 16.5 KB [n][row]
  __shared__ float2 sCp[16][128];    // 16.4 KB [n][col]
  int tid = threadIdx.x;
  int kidx = blockIdx.x >> 5;        // 0..15
  int rt   = blockIdx.x & 31;        // 0..31
  int rowBase = rt * 128;            // chunk-local
  int rg = tid & 15;                 // rows rg + 16j
  int cg = tid >> 4;                 // cols cg*8 .. +7
  int c0 = cg * 8;
  float acc[8][8];
  #pragma unroll
  for (int jj = 0; jj < 8; ++jj)
    #pragma unroll
    for (int q = 0; q < 8; ++q) acc[jj][q] = 0.f;

  #pragma unroll 1
  for (int nh = 0; nh < 4; ++nh) {
    __syncthreads();
    // stage sS2t [16 n][128 row]: 1024 float4, 4/thread
    #pragma unroll
    for (int it = 0; it < 4; ++it) {
      int e = tid + it * 256;          // 0..1023
      int n2 = (e & 7) * 2;
      int row = e >> 3;                // 0..127
      float4 v = *(const float4*)(S2 + (size_t)(rowBase + row) * 1024
                                     + kidx * 64 + nh * 16 + n2);
      sS2t[n2][row]     = make_float2(v.x, v.y);
      sS2t[n2 + 1][row] = make_float2(v.z, v.w);
    }
    // stage sCp [16 n][128 col]: 1024 float4, 4/thread
    #pragma unroll
    for (int it = 0; it < 4; ++it) {
      int e = tid + it * 256;
      int col2 = (e & 63) * 2;
      int n = e >> 6;                  // 0..15
      float4 v = *(const float4*)(Cp + (size_t)(kidx * 64 + nh * 16 + n) * MOUT + col2);
      *(float4*)&sCp[n][col2] = v;
    }
    __syncthreads();
    #pragma unroll 4
    for (int n = 0; n < 16; ++n) {
      float2 a[8];
      #pragma unroll
      for (int jj = 0; jj < 8; ++jj) a[jj] = sS2t[n][rg + jj * 16];
      float4 w[4];
      #pragma unroll
      for (int q = 0; q < 4; ++q) w[q] = *(const float4*)&sCp[n][c0 + q * 2];
      float cx[8] = {w[0].x, w[0].z, w[1].x, w[1].z, w[2].x, w[2].z, w[3].x, w[3].z};
      float cy[8] = {w[0].y, w[0].w, w[1].y, w[1].w, w[2].y, w[2].w, w[3].y, w[3].w};
      #pragma unroll
      for (int jj = 0; jj < 8; ++jj)
        #pragma unroll
        for (int q = 0; q < 8; ++q)
          acc[jj][q] = __fadd_rn(acc[jj][q],
              __fsub_rn(__fmul_rn(a[jj].x, cx[q]), __fmul_rn(a[jj].y, cy[q])));
    }
  }
  // epilogue: P[kidx][row][col] = (accn + xc*D) + Do
  float dv[8], ovv[8];
  *(float4*)&dv[0]  = *(const float4*)(D + kidx * MOUT + c0);
  *(float4*)&dv[4]  = *(const float4*)(D + kidx * MOUT + c0 + 4);
  *(float4*)&ovv[0] = *(const float4*)(Dov + c0);
  *(float4*)&ovv[4] = *(const float4*)(Dov + c0 + 4);
  #pragma unroll
  for (int jj = 0; jj < 8; ++jj) {
    int row = rowBase + rg + jj * 16;
    float xv = xcq[(size_t)(c * 4096 + row) * KP + kidx];
    float res[8];
    #pragma unroll
    for (int q = 0; q < 8; ++q)
      res[q] = __fadd_rn(__fadd_rn(acc[jj][q], __fmul_rn(xv, dv[q])), ovv[q]);
    float* pp = P + ((size_t)kidx * 4096 + row) * MOUT + c0;
    *(float4*)pp       = make_float4(res[0], res[1], res[2], res[3]);
    *(float4*)(pp + 4) = make_float4(res[4], res[5], res[6], res[7]);
  }
}

// ---------------------------------------------------------------------------
// out = (P0 + ... + P15)/16, k ascending (bit-matches rounds 4-6 msum).
__global__ __launch_bounds__(256) void k_combine(const float* __restrict__ P,
                     float* __restrict__ out, int c) {
  int idx = blockIdx.x * 256 + threadIdx.x;   // 131072 float4s
  int r  = idx >> 5;
  int m4 = (idx & 31) * 4;
  float4 s = *(const float4*)(P + (size_t)r * MOUT + m4);
  #pragma unroll
  for (int k = 1; k < KP; ++k) {
    float4 p = *(const float4*)(P + ((size_t)k * 4096 + r) * MOUT + m4);
    s.x = __fadd_rn(s.x, p.x);
    s.y = __fadd_rn(s.y, p.y);
    s.z = __fadd_rn(s.z, p.z);
    s.w = __fadd_rn(s.w, p.w);
  }
  int rg = c * 4096 + r;
  int t = rg >> 4, b = rg & 15;
  float4 res;
  res.x = __fdiv_rn(s.x, 16.0f);
  res.y = __fdiv_rn(s.y, 16.0f);
  res.z = __fdiv_rn(s.z, 16.0f);
  res.w = __fdiv_rn(s.w, 16.0f);
  *(float4*)(out + ((size_t)b * TLEN + t) * MOUT + m4) = res;
}

// ---------------------------------------------------------------------------
extern "C" void kernel_launch(void* const* d_in, const int* in_sizes, int n_in,
                              void* d_out, int out_size, void* d_ws, size_t ws_size,
                              hipStream_t stream) {
  const float* x     = (const float*)d_in[0];
  const float* R     = (const float*)d_in[1];
  const float* theta = (const float*)d_in[2];
  const float* C     = (const float*)d_in[3];
  const float* D     = (const float*)d_in[4];
  const float* Do    = (const float*)d_in[5];
  float* out = (float*)d_out;
  float* ws  = (float*)d_ws;
  float*  xcq = ws + XCQ_OFF;
  float2* lam = (float2*)(ws + LAM_OFF);
  float2* Bq  = (float2*)(ws + BQ_OFF);
  float2* Cp  = (float2*)(ws + CP_OFF);
  float*  st  = ws + ST_OFF;
  float2* S2  = (float2*)(ws + S2_OFF);
  float*  P   = ws + P_OFF;

  hipLaunchKernelGGL(k_lam_B, dim3(256),  dim3(256), 0, stream, theta, lam, Bq);
  hipLaunchKernelGGL(k_Cp,    dim3(1024), dim3(128), 0, stream, theta, C, Cp);
  hipLaunchKernelGGL(k_xc,    dim3(1024), dim3(256), 0, stream, x, R, xcq);
  for (int c = 0; c < NCHUNK; ++c) {
    hipLaunchKernelGGL(k_scan,    dim3(256), dim3(64),  0, stream, lam, Bq, xcq, S2, st, c);
    hipLaunchKernelGGL(k_y,       dim3(512), dim3(256), 0, stream, S2, Cp, xcq, D, Do, P, c);
    hipLaunchKernelGGL(k_combine, dim3(512), dim3(256), 0, stream, P, out, c);
  }
}

// Round 14
// 396.254 us; speedup vs baseline: 1.4688x; 1.4688x over previous
//
#include <hip/hip_runtime.h>
#include <math.h>

#define TLEN 1024
#define BSZ  16
#define DIN  128
#define KP   16
#define NEIG 64
#define MOUT 128
#define CHUNK_T 256
#define NCHUNK  4

// ws layout (float units)
static constexpr size_t XCQ_OFF = 0;        // 262144: xc f32 [t][b][k]
static constexpr size_t LAM_OFF = 262144;   // 2048:  lambda c32
static constexpr size_t BQ_OFF  = 264192;   // 2048:  B' c32
static constexpr size_t CP_OFF  = 266240;   // 262144: Cp c32 [(k*64+j)*128+m]
static constexpr size_t ST_OFF  = 528384;   // 65536: scan state
static constexpr size_t S2_OFF  = 593920;   // 8388608: s2 chunk [4096][1024] float2
static constexpr size_t P_OFF   = 8982528;  // 8388608: k-split partials [16][4096][128]
// total: 17,371,136 floats = 69.48 MB (proven usable)

__device__ __forceinline__ float f32cos(float x) { return (float)cos((double)x); }
__device__ __forceinline__ float f32sin(float x) { return (float)sin((double)x); }

__device__ __forceinline__ float2 cdiv32(float ar, float ai, float cr, float ci) {
  float2 o;
  if (fabsf(ci) <= fabsf(cr)) {
    float rat = __fdiv_rn(ci, cr);
    float scl = __fdiv_rn(1.0f, __fadd_rn(cr, __fmul_rn(ci, rat)));
    o.x = __fmul_rn(__fadd_rn(ar, __fmul_rn(ai, rat)), scl);
    o.y = __fmul_rn(__fsub_rn(ai, __fmul_rn(ar, rat)), scl);
  } else {
    float rat = __fdiv_rn(cr, ci);
    float scl = __fdiv_rn(1.0f, __fadd_rn(ci, __fmul_rn(cr, rat)));
    o.x = __fmul_rn(__fadd_rn(__fmul_rn(ar, rat), ai), scl);
    o.y = __fmul_rn(__fsub_rn(__fmul_rn(ai, rat), ar), scl);
  }
  return o;
}

// ---------------------------------------------------------------------------
__global__ __launch_bounds__(256) void k_lam_B(const float* __restrict__ theta,
                        float2* __restrict__ lam, float2* __restrict__ Bq) {
  __shared__ float2 terms[4][64];
  int wid  = threadIdx.x >> 6;
  int lane = threadIdx.x & 63;
  int idx = blockIdx.x * 4 + wid;
  int k = idx >> 6, j = idx & 63;
  float thj = (j < 32) ? theta[k * 32 + j] : -theta[k * 32 + (j - 32)];
  float ljr = f32cos(thj), lji = f32sin(thj);
  float2 tm = make_float2(0.f, 0.f);
  if (lane != j) {
    int i = lane;
    float thi = (i < 32) ? theta[k * 32 + i] : -theta[k * 32 + (i - 32)];
    float lir = f32cos(thi), lii = f32sin(thi);
    float2 r = cdiv32(lir, lii, ljr, lji);
    float tr = __fsub_rn(1.0f, r.x);
    float ti = __fsub_rn(0.0f, r.y);
    double h = sqrt((double)tr * tr + (double)ti * ti);
    tm.x = (float)log(h);
    tm.y = (float)atan2((double)ti, (double)tr);
  }
  terms[wid][lane] = tm;
  __syncthreads();
  if (lane == 0) {
    lam[idx] = make_float2(ljr, lji);
    float sr = 0.f, si = 0.f;
    for (int i = 0; i < NEIG; ++i) {
      sr = __fadd_rn(sr, terms[wid][i].x);
      si = __fadd_rn(si, terms[wid][i].y);
    }
    float er = (float)exp((double)(-sr));
    float cc = f32cos(-si), ss = f32sin(-si);
    Bq[idx] = make_float2(__fmul_rn(er, cc), __fmul_rn(er, ss));
  }
}

// ---------------------------------------------------------------------------
__global__ __launch_bounds__(128) void k_Cp(const float* __restrict__ theta,
                     const float* __restrict__ C, float2* __restrict__ Cp) {
  __shared__ float2 sU[64];
  __shared__ float  sC[128][65];
  int tid = threadIdx.x;
  int kj = blockIdx.x;
  int j = kj & 63, k = kj >> 6;
  float lnim = (j < 32) ? theta[k * 32 + j] : -theta[k * 32 + (j - 32)];
  if (tid < 64) {
    int i = tid;
    float p = (float)(63 - i);
    float ph = -__fmul_rn(p, lnim);
    sU[i] = make_float2(f32cos(ph), f32sin(ph));
  }
  const float* Ck = C + ((size_t)k << 13);
  for (int e = tid; e < 128 * 64; e += 128) {
    sC[e >> 6][e & 63] = Ck[e];
  }
  __syncthreads();
  int m = tid;
  float ar = 0.f, ai = 0.f;
  #pragma unroll 8
  for (int i = 0; i < NEIG; ++i) {
    float Cv = sC[m][i];
    float2 U = sU[i];
    ar = __fadd_rn(ar, __fmul_rn(Cv, U.x));
    ai = __fadd_rn(ai, __fmul_rn(Cv, U.y));
  }
  Cp[(size_t)(k * 64 + j) * MOUT + m] = make_float2(ar, ai);
}

// ---------------------------------------------------------------------------
__global__ __launch_bounds__(256) void k_xc(const float* __restrict__ x,
                     const float* __restrict__ R, float* __restrict__ xcq) {
  __shared__ float sX[16][132];
  __shared__ float sR[128][16];
  int tid = threadIdx.x;
  int rBase = blockIdx.x * 16;
  for (int e = tid; e < DIN * KP; e += 256) sR[e >> 4][e & 15] = R[e];
  #pragma unroll
  for (int it = 0; it < 2; ++it) {
    int e = tid + it * 256;
    int row = e >> 5, q = e & 31;
    int g = rBase + row;
    int t = g >> 4, b = g & 15;
    float4 v = *(const float4*)(x + ((size_t)b * TLEN + t) * DIN + q * 4);
    *(float4*)&sX[row][q * 4] = v;
  }
  __syncthreads();
  int r = tid >> 4, k = tid & 15;
  double acc = 0.0;
  #pragma unroll 16
  for (int d = 0; d < DIN; ++d)
    acc = fma((double)sX[r][d], (double)sR[d][k], acc);
  xcq[(size_t)(rBase + r) * KP + k] = (float)acc;
}

// ---------------------------------------------------------------------------
// Scan v6 (reverted to round 12 exactly): single pass, 1 mode/lane, register
// alpha-pipeline in batches of 8. Bit-identical per-step op sequence.
__global__ __launch_bounds__(64) void k_scan(const float2* __restrict__ lam,
                        const float2* __restrict__ Bq,
                        const float* __restrict__ xcq,
                        float2* __restrict__ S2,
                        float* __restrict__ state, int c) {
  __shared__ float sXq[CHUNK_T];
  int j = threadIdx.x;
  int chain = blockIdx.x;              // b*16 + k
  int b = chain >> 4, k = chain & 15;
  int mode = k * 64 + j;
  int t0 = c * CHUNK_T;
  int tlBeg = (c == 0) ? 1 : 0;
  for (int i = j; i < CHUNK_T; i += 64) {
    int g = t0 + tlBeg - 1 + i;
    sXq[i] = xcq[(size_t)g * (BSZ * KP) + b * KP + k];
  }
  __syncthreads();
  float lr = lam[mode].x, li = lam[mode].y;
  float Br = Bq[mode].x,  Bi = Bq[mode].y;
  float* st = state + (size_t)(chain * 64 + j) * 4;
  float s1r, s1i, s2r, s2i;
  if (c == 0) { s1r = s1i = s2r = s2i = 0.f; }
  else        { s1r = st[0]; s1i = st[1]; s2r = st[2]; s2i = st[3]; }
  if (c == 0)
    S2[(size_t)(0 * BSZ + b) * 1024 + mode] = make_float2(s2r, s2i);

  int tl = tlBeg;
  for (; tl + 8 <= CHUNK_T; tl += 8) {
    float als[8];
    #pragma unroll
    for (int u = 0; u < 8; ++u) {
      float xq = sXq[tl - tlBeg + u];
      float lsr = __fsub_rn(__fmul_rn(lr, s1r), __fmul_rn(li, s1i));
      float lsi = __fadd_rn(__fmul_rn(lr, s1i), __fmul_rn(li, s1r));
      float h  = (float)sqrt((double)lsr * lsr + (double)lsi * lsi);
      als[u] = __fdiv_rn(1.0f, __fsqrt_rn(__fadd_rn(1.0f, __fmul_rn(h, h))));
      float bxr = __fmul_rn(xq, Br), bxi = __fmul_rn(xq, Bi);
      s1r = __fadd_rn(lsr, bxr);
      s1i = __fadd_rn(lsi, bxi);
    }
    #pragma unroll
    for (int u = 0; u < 8; ++u) {
      float xq = sXq[tl - tlBeg + u];
      float al = als[u];
      float bxr = __fmul_rn(xq, Br), bxi = __fmul_rn(xq, Bi);
      float a2r = __fmul_rn(al, lr), a2i = __fmul_rn(al, li);
      float t2r = __fsub_rn(__fmul_rn(a2r, s2r), __fmul_rn(a2i, s2i));
      float t2i = __fadd_rn(__fmul_rn(a2r, s2i), __fmul_rn(a2i, s2r));
      s2r = __fadd_rn(t2r, bxr);
      s2i = __fadd_rn(t2i, bxi);
      S2[(size_t)((tl + u) * BSZ + b) * 1024 + mode] = make_float2(s2r, s2i);
    }
  }
  for (; tl < CHUNK_T; ++tl) {
    float xq = sXq[tl - tlBeg];
    float lsr = __fsub_rn(__fmul_rn(lr, s1r), __fmul_rn(li, s1i));
    float lsi = __fadd_rn(__fmul_rn(lr, s1i), __fmul_rn(li, s1r));
    float h  = (float)sqrt((double)lsr * lsr + (double)lsi * lsi);
    float al = __fdiv_rn(1.0f, __fsqrt_rn(__fadd_rn(1.0f, __fmul_rn(h, h))));
    float bxr = __fmul_rn(xq, Br), bxi = __fmul_rn(xq, Bi);
    float a2r = __fmul_rn(al, lr), a2i = __fmul_rn(al, li);
    float t2r = __fsub_rn(__fmul_rn(a2r, s2r), __fmul_rn(a2i, s2i));
    float t2i = __fadd_rn(__fmul_rn(a2r, s2i), __fmul_rn(a2i, s2r));
    s2r = __fadd_rn(t2r, bxr);
    s2i = __fadd_rn(t2i, bxi);
    s1r = __fadd_rn(lsr, bxr);
    s1i = __fadd_rn(lsi, bxi);
    S2[(size_t)(tl * BSZ + b) * 1024 + mode] = make_float2(s2r, s2i);
  }
  st[0] = s1r; st[1] = s1i; st[2] = s2r; st[3] = s2i;
}

// ---------------------------------------------------------------------------
// k_y v11 = v10 (4 n-phases, 33 KB LDS, 4 blocks/CU, natural VGPR) +
// reg-staged next-phase prefetch: per phase, {barrier; regs->LDS; barrier;
// issue next phase's global loads; compute}. Next-tile HBM latency hides
// under the current phase's 2048 FMAs. Arithmetic identical to R4-13.
__global__ __launch_bounds__(256) void k_y(const float2* __restrict__ S2,
                     const float2* __restrict__ Cp, const float* __restrict__ xcq,
                     const float* __restrict__ D, const float* __restrict__ Dov,
                     float* __restrict__ P, int c) {
  __shared__ float2 sS2t[16][129];   // 16.5 KB [n][row]
  __shared__ float2 sCp[16][128];    // 16.4 KB [n][col]
  int tid = threadIdx.x;
  int kidx = blockIdx.x >> 5;        // 0..15
  int rt   = blockIdx.x & 31;        // 0..31
  int rowBase = rt * 128;            // chunk-local
  int rg = tid & 15;                 // rows rg + 16j
  int cg = tid >> 4;                 // cols cg*8 .. +7
  int c0 = cg * 8;
  float acc[8][8];
  #pragma unroll
  for (int jj = 0; jj < 8; ++jj)
    #pragma unroll
    for (int q = 0; q < 8; ++q) acc[jj][q] = 0.f;

  // per-thread staging addresses (constant across phases except nh offset)
  int a_n2[4], a_row[4], w_n[4], w_col2[4];
  #pragma unroll
  for (int it = 0; it < 4; ++it) {
    int e = tid + it * 256;
    a_n2[it] = (e & 7) * 2;  a_row[it] = e >> 3;       // sS2t element
    w_n[it] = e >> 6;        w_col2[it] = (e & 63) * 2; // sCp element
  }

  float4 regA[4], regB[4];
  // prologue: load phase 0 into regs
  #pragma unroll
  for (int it = 0; it < 4; ++it) {
    regA[it] = *(const float4*)(S2 + (size_t)(rowBase + a_row[it]) * 1024
                                   + kidx * 64 + a_n2[it]);
    regB[it] = *(const float4*)(Cp + (size_t)(kidx * 64 + w_n[it]) * MOUT + w_col2[it]);
  }

  #pragma unroll 1
  for (int nh = 0; nh < 4; ++nh) {
    __syncthreads();                 // prev compute done -> LDS reusable
    #pragma unroll
    for (int it = 0; it < 4; ++it) {
      sS2t[a_n2[it]][a_row[it]]     = make_float2(regA[it].x, regA[it].y);
      sS2t[a_n2[it] + 1][a_row[it]] = make_float2(regA[it].z, regA[it].w);
      *(float4*)&sCp[w_n[it]][w_col2[it]] = regB[it];
    }
    __syncthreads();
    if (nh < 3) {                    // issue next phase's loads (overlap compute)
      #pragma unroll
      for (int it = 0; it < 4; ++it) {
        regA[it] = *(const float4*)(S2 + (size_t)(rowBase + a_row[it]) * 1024
                                       + kidx * 64 + (nh + 1) * 16 + a_n2[it]);
        regB[it] = *(const float4*)(Cp + (size_t)(kidx * 64 + (nh + 1) * 16 + w_n[it]) * MOUT
                                       + w_col2[it]);
      }
    }
    #pragma unroll 4
    for (int n = 0; n < 16; ++n) {
      float2 a[8];
      #pragma unroll
      for (int jj = 0; jj < 8; ++jj) a[jj] = sS2t[n][rg + jj * 16];
      float4 w[4];
      #pragma unroll
      for (int q = 0; q < 4; ++q) w[q] = *(const float4*)&sCp[n][c0 + q * 2];
      float cx[8] = {w[0].x, w[0].z, w[1].x, w[1].z, w[2].x, w[2].z, w[3].x, w[3].z};
      float cy[8] = {w[0].y, w[0].w, w[1].y, w[1].w, w[2].y, w[2].w, w[3].y, w[3].w};
      #pragma unroll
      for (int jj = 0; jj < 8; ++jj)
        #pragma unroll
        for (int q = 0; q < 8; ++q)
          acc[jj][q] = __fadd_rn(acc[jj][q],
              __fsub_rn(__fmul_rn(a[jj].x, cx[q]), __fmul_rn(a[jj].y, cy[q])));
    }
  }
  // epilogue: P[kidx][row][col] = (accn + xc*D) + Do
  float dv[8], ovv[8];
  *(float4*)&dv[0]  = *(const float4*)(D + kidx * MOUT + c0);
  *(float4*)&dv[4]  = *(const float4*)(D + kidx * MOUT + c0 + 4);
  *(float4*)&ovv[0] = *(const float4*)(Dov + c0);
  *(float4*)&ovv[4] = *(const float4*)(Dov + c0 + 4);
  #pragma unroll
  for (int jj = 0; jj < 8; ++jj) {
    int row = rowBase + rg + jj * 16;
    float xv = xcq[(size_t)(c * 4096 + row) * KP + kidx];
    float res[8];
    #pragma unroll
    for (int q = 0; q < 8; ++q)
      res[q] = __fadd_rn(__fadd_rn(acc[jj][q], __fmul_rn(xv, dv[q])), ovv[q]);
    float* pp = P + ((size_t)kidx * 4096 + row) * MOUT + c0;
    *(float4*)pp       = make_float4(res[0], res[1], res[2], res[3]);
    *(float4*)(pp + 4) = make_float4(res[4], res[5], res[6], res[7]);
  }
}

// ---------------------------------------------------------------------------
// out = (P0 + ... + P15)/16, k ascending (bit-matches rounds 4-6 msum).
__global__ __launch_bounds__(256) void k_combine(const float* __restrict__ P,
                     float* __restrict__ out, int c) {
  int idx = blockIdx.x * 256 + threadIdx.x;   // 131072 float4s
  int r  = idx >> 5;
  int m4 = (idx & 31) * 4;
  float4 s = *(const float4*)(P + (size_t)r * MOUT + m4);
  #pragma unroll
  for (int k = 1; k < KP; ++k) {
    float4 p = *(const float4*)(P + ((size_t)k * 4096 + r) * MOUT + m4);
    s.x = __fadd_rn(s.x, p.x);
    s.y = __fadd_rn(s.y, p.y);
    s.z = __fadd_rn(s.z, p.z);
    s.w = __fadd_rn(s.w, p.w);
  }
  int rg = c * 4096 + r;
  int t = rg >> 4, b = rg & 15;
  float4 res;
  res.x = __fdiv_rn(s.x, 16.0f);
  res.y = __fdiv_rn(s.y, 16.0f);
  res.z = __fdiv_rn(s.z, 16.0f);
  res.w = __fdiv_rn(s.w, 16.0f);
  *(float4*)(out + ((size_t)b * TLEN + t) * MOUT + m4) = res;
}

// ---------------------------------------------------------------------------
extern "C" void kernel_launch(void* const* d_in, const int* in_sizes, int n_in,
                              void* d_out, int out_size, void* d_ws, size_t ws_size,
                              hipStream_t stream) {
  const float* x     = (const float*)d_in[0];
  const float* R     = (const float*)d_in[1];
  const float* theta = (const float*)d_in[2];
  const float* C     = (const float*)d_in[3];
  const float* D     = (const float*)d_in[4];
  const float* Do    = (const float*)d_in[5];
  float* out = (float*)d_out;
  float* ws  = (float*)d_ws;
  float*  xcq = ws + XCQ_OFF;
  float2* lam = (float2*)(ws + LAM_OFF);
  float2* Bq  = (float2*)(ws + BQ_OFF);
  float2* Cp  = (float2*)(ws + CP_OFF);
  float*  st  = ws + ST_OFF;
  float2* S2  = (float2*)(ws + S2_OFF);
  float*  P   = ws + P_OFF;

  hipLaunchKernelGGL(k_lam_B, dim3(256),  dim3(256), 0, stream, theta, lam, Bq);
  hipLaunchKernelGGL(k_Cp,    dim3(1024), dim3(128), 0, stream, theta, C, Cp);
  hipLaunchKernelGGL(k_xc,    dim3(1024), dim3(256), 0, stream, x, R, xcq);
  for (int c = 0; c < NCHUNK; ++c) {
    hipLaunchKernelGGL(k_scan,    dim3(256), dim3(64),  0, stream, lam, Bq, xcq, S2, st, c);
    hipLaunchKernelGGL(k_y,       dim3(512), dim3(256), 0, stream, S2, Cp, xcq, D, Do, P, c);
    hipLaunchKernelGGL(k_combine, dim3(512), dim3(256), 0, stream, P, out, c);
  }
}

// Round 15
// 372.050 us; speedup vs baseline: 1.5644x; 1.0651x over previous
//
#include <hip/hip_runtime.h>
#include <math.h>

#define TLEN 1024
#define BSZ  16
#define DIN  128
#define KP   16
#define NEIG 64
#define MOUT 128
#define CHUNK_T 256
#define NCHUNK  4

// ws layout (float units)
static constexpr size_t XCQ_OFF = 0;        // 262144: xc f32 [t][b][k]
static constexpr size_t LAM_OFF = 262144;   // 2048:  lambda c32
static constexpr size_t BQ_OFF  = 264192;   // 2048:  B' c32
static constexpr size_t CP_OFF  = 266240;   // 262144: Cp c32 [(k*64+j)*128+m]
static constexpr size_t ST_OFF  = 528384;   // 65536: scan state
static constexpr size_t S2_OFF  = 593920;   // 8388608: s2 chunk [4096][1024] float2
static constexpr size_t P_OFF   = 8982528;  // 8388608: k-split partials [16][4096][128]
// total: 17,371,136 floats = 69.48 MB (proven usable)

__device__ __forceinline__ float f32cos(float x) { return (float)cos((double)x); }
__device__ __forceinline__ float f32sin(float x) { return (float)sin((double)x); }

__device__ __forceinline__ float2 cdiv32(float ar, float ai, float cr, float ci) {
  float2 o;
  if (fabsf(ci) <= fabsf(cr)) {
    float rat = __fdiv_rn(ci, cr);
    float scl = __fdiv_rn(1.0f, __fadd_rn(cr, __fmul_rn(ci, rat)));
    o.x = __fmul_rn(__fadd_rn(ar, __fmul_rn(ai, rat)), scl);
    o.y = __fmul_rn(__fsub_rn(ai, __fmul_rn(ar, rat)), scl);
  } else {
    float rat = __fdiv_rn(cr, ci);
    float scl = __fdiv_rn(1.0f, __fadd_rn(ci, __fmul_rn(cr, rat)));
    o.x = __fmul_rn(__fadd_rn(__fmul_rn(ar, rat), ai), scl);
    o.y = __fmul_rn(__fsub_rn(__fmul_rn(ai, rat), ar), scl);
  }
  return o;
}

// ---------------------------------------------------------------------------
__global__ __launch_bounds__(256) void k_lam_B(const float* __restrict__ theta,
                        float2* __restrict__ lam, float2* __restrict__ Bq) {
  __shared__ float2 terms[4][64];
  int wid  = threadIdx.x >> 6;
  int lane = threadIdx.x & 63;
  int idx = blockIdx.x * 4 + wid;
  int k = idx >> 6, j = idx & 63;
  float thj = (j < 32) ? theta[k * 32 + j] : -theta[k * 32 + (j - 32)];
  float ljr = f32cos(thj), lji = f32sin(thj);
  float2 tm = make_float2(0.f, 0.f);
  if (lane != j) {
    int i = lane;
    float thi = (i < 32) ? theta[k * 32 + i] : -theta[k * 32 + (i - 32)];
    float lir = f32cos(thi), lii = f32sin(thi);
    float2 r = cdiv32(lir, lii, ljr, lji);
    float tr = __fsub_rn(1.0f, r.x);
    float ti = __fsub_rn(0.0f, r.y);
    double h = sqrt((double)tr * tr + (double)ti * ti);
    tm.x = (float)log(h);
    tm.y = (float)atan2((double)ti, (double)tr);
  }
  terms[wid][lane] = tm;
  __syncthreads();
  if (lane == 0) {
    lam[idx] = make_float2(ljr, lji);
    float sr = 0.f, si = 0.f;
    for (int i = 0; i < NEIG; ++i) {
      sr = __fadd_rn(sr, terms[wid][i].x);
      si = __fadd_rn(si, terms[wid][i].y);
    }
    float er = (float)exp((double)(-sr));
    float cc = f32cos(-si), ss = f32sin(-si);
    Bq[idx] = make_float2(__fmul_rn(er, cc), __fmul_rn(er, ss));
  }
}

// ---------------------------------------------------------------------------
__global__ __launch_bounds__(128) void k_Cp(const float* __restrict__ theta,
                     const float* __restrict__ C, float2* __restrict__ Cp) {
  __shared__ float2 sU[64];
  __shared__ float  sC[128][65];
  int tid = threadIdx.x;
  int kj = blockIdx.x;
  int j = kj & 63, k = kj >> 6;
  float lnim = (j < 32) ? theta[k * 32 + j] : -theta[k * 32 + (j - 32)];
  if (tid < 64) {
    int i = tid;
    float p = (float)(63 - i);
    float ph = -__fmul_rn(p, lnim);
    sU[i] = make_float2(f32cos(ph), f32sin(ph));
  }
  const float* Ck = C + ((size_t)k << 13);
  for (int e = tid; e < 128 * 64; e += 128) {
    sC[e >> 6][e & 63] = Ck[e];
  }
  __syncthreads();
  int m = tid;
  float ar = 0.f, ai = 0.f;
  #pragma unroll 8
  for (int i = 0; i < NEIG; ++i) {
    float Cv = sC[m][i];
    float2 U = sU[i];
    ar = __fadd_rn(ar, __fmul_rn(Cv, U.x));
    ai = __fadd_rn(ai, __fmul_rn(Cv, U.y));
  }
  Cp[(size_t)(k * 64 + j) * MOUT + m] = make_float2(ar, ai);
}

// ---------------------------------------------------------------------------
__global__ __launch_bounds__(256) void k_xc(const float* __restrict__ x,
                     const float* __restrict__ R, float* __restrict__ xcq) {
  __shared__ float sX[16][132];
  __shared__ float sR[128][16];
  int tid = threadIdx.x;
  int rBase = blockIdx.x * 16;
  for (int e = tid; e < DIN * KP; e += 256) sR[e >> 4][e & 15] = R[e];
  #pragma unroll
  for (int it = 0; it < 2; ++it) {
    int e = tid + it * 256;
    int row = e >> 5, q = e & 31;
    int g = rBase + row;
    int t = g >> 4, b = g & 15;
    float4 v = *(const float4*)(x + ((size_t)b * TLEN + t) * DIN + q * 4);
    *(float4*)&sX[row][q * 4] = v;
  }
  __syncthreads();
  int r = tid >> 4, k = tid & 15;
  double acc = 0.0;
  #pragma unroll 16
  for (int d = 0; d < DIN; ++d)
    acc = fma((double)sX[r][d], (double)sR[d][k], acc);
  xcq[(size_t)(rBase + r) * KP + k] = (float)acc;
}

// ---------------------------------------------------------------------------
// Scan v6 (round 12, proven): single pass, 1 mode/lane, register alpha
// pipeline in batches of 8. Bit-identical per-step op sequence.
__global__ __launch_bounds__(64) void k_scan(const float2* __restrict__ lam,
                        const float2* __restrict__ Bq,
                        const float* __restrict__ xcq,
                        float2* __restrict__ S2,
                        float* __restrict__ state, int c) {
  __shared__ float sXq[CHUNK_T];
  int j = threadIdx.x;
  int chain = blockIdx.x;              // b*16 + k
  int b = chain >> 4, k = chain & 15;
  int mode = k * 64 + j;
  int t0 = c * CHUNK_T;
  int tlBeg = (c == 0) ? 1 : 0;
  for (int i = j; i < CHUNK_T; i += 64) {
    int g = t0 + tlBeg - 1 + i;
    sXq[i] = xcq[(size_t)g * (BSZ * KP) + b * KP + k];
  }
  __syncthreads();
  float lr = lam[mode].x, li = lam[mode].y;
  float Br = Bq[mode].x,  Bi = Bq[mode].y;
  float* st = state + (size_t)(chain * 64 + j) * 4;
  float s1r, s1i, s2r, s2i;
  if (c == 0) { s1r = s1i = s2r = s2i = 0.f; }
  else        { s1r = st[0]; s1i = st[1]; s2r = st[2]; s2i = st[3]; }
  if (c == 0)
    S2[(size_t)(0 * BSZ + b) * 1024 + mode] = make_float2(s2r, s2i);

  int tl = tlBeg;
  for (; tl + 8 <= CHUNK_T; tl += 8) {
    float als[8];
    #pragma unroll
    for (int u = 0; u < 8; ++u) {
      float xq = sXq[tl - tlBeg + u];
      float lsr = __fsub_rn(__fmul_rn(lr, s1r), __fmul_rn(li, s1i));
      float lsi = __fadd_rn(__fmul_rn(lr, s1i), __fmul_rn(li, s1r));
      float h  = (float)sqrt((double)lsr * lsr + (double)lsi * lsi);
      als[u] = __fdiv_rn(1.0f, __fsqrt_rn(__fadd_rn(1.0f, __fmul_rn(h, h))));
      float bxr = __fmul_rn(xq, Br), bxi = __fmul_rn(xq, Bi);
      s1r = __fadd_rn(lsr, bxr);
      s1i = __fadd_rn(lsi, bxi);
    }
    #pragma unroll
    for (int u = 0; u < 8; ++u) {
      float xq = sXq[tl - tlBeg + u];
      float al = als[u];
      float bxr = __fmul_rn(xq, Br), bxi = __fmul_rn(xq, Bi);
      float a2r = __fmul_rn(al, lr), a2i = __fmul_rn(al, li);
      float t2r = __fsub_rn(__fmul_rn(a2r, s2r), __fmul_rn(a2i, s2i));
      float t2i = __fadd_rn(__fmul_rn(a2r, s2i), __fmul_rn(a2i, s2r));
      s2r = __fadd_rn(t2r, bxr);
      s2i = __fadd_rn(t2i, bxi);
      S2[(size_t)((tl + u) * BSZ + b) * 1024 + mode] = make_float2(s2r, s2i);
    }
  }
  for (; tl < CHUNK_T; ++tl) {
    float xq = sXq[tl - tlBeg];
    float lsr = __fsub_rn(__fmul_rn(lr, s1r), __fmul_rn(li, s1i));
    float lsi = __fadd_rn(__fmul_rn(lr, s1i), __fmul_rn(li, s1r));
    float h  = (float)sqrt((double)lsr * lsr + (double)lsi * lsi);
    float al = __fdiv_rn(1.0f, __fsqrt_rn(__fadd_rn(1.0f, __fmul_rn(h, h))));
    float bxr = __fmul_rn(xq, Br), bxi = __fmul_rn(xq, Bi);
    float a2r = __fmul_rn(al, lr), a2i = __fmul_rn(al, li);
    float t2r = __fsub_rn(__fmul_rn(a2r, s2r), __fmul_rn(a2i, s2i));
    float t2i = __fadd_rn(__fmul_rn(a2r, s2i), __fmul_rn(a2i, s2r));
    s2r = __fadd_rn(t2r, bxr);
    s2i = __fadd_rn(t2i, bxi);
    s1r = __fadd_rn(lsr, bxr);
    s1i = __fadd_rn(lsi, bxi);
    S2[(size_t)(tl * BSZ + b) * 1024 + mode] = make_float2(s2r, s2i);
  }
  st[0] = s1r; st[1] = s1i; st[2] = s2r; st[3] = s2i;
}

// ---------------------------------------------------------------------------
// k_y v12: split-k x16 x 64 row-tiles (BM=64) = 1024 blocks -> 4 blocks/CU,
// 16 waves/CU. 256 threads; microtile 4 rows (rg+16j) x 8 cols; 4 n-phases
// of 16; LDS 24.9 KB; natural VGPR (~64). Arithmetic identical to R4-14:
// n ascending 0..63 per (row,col); epilogue (acc + xc*D) + Do; P[k] partials.
__global__ __launch_bounds__(256) void k_y(const float2* __restrict__ S2,
                     const float2* __restrict__ Cp, const float* __restrict__ xcq,
                     const float* __restrict__ D, const float* __restrict__ Dov,
                     float* __restrict__ P, int c) {
  __shared__ float2 sS2t[16][65];    // 8.3 KB [n][row]
  __shared__ float2 sCp[16][130];    // 16.6 KB [n][col]
  int tid = threadIdx.x;
  int kidx = blockIdx.x >> 6;        // 0..15
  int rt   = blockIdx.x & 63;        // 0..63
  int rowBase = rt * 64;             // chunk-local
  int rg = tid & 15;                 // rows rg + 16j (j=0..3)
  int cg = tid >> 4;                 // cols cg*8 .. +7
  int c0 = cg * 8;
  float acc[4][8];
  #pragma unroll
  for (int jj = 0; jj < 4; ++jj)
    #pragma unroll
    for (int q = 0; q < 8; ++q) acc[jj][q] = 0.f;

  #pragma unroll 1
  for (int nh = 0; nh < 4; ++nh) {
    __syncthreads();
    // stage sS2t [16 n][64 row]: 512 float4, 2/thread
    #pragma unroll
    for (int it = 0; it < 2; ++it) {
      int e = tid + it * 256;          // 0..511
      int n2 = (e & 7) * 2;
      int row = e >> 3;                // 0..63
      float4 v = *(const float4*)(S2 + (size_t)(rowBase + row) * 1024
                                     + kidx * 64 + nh * 16 + n2);
      sS2t[n2][row]     = make_float2(v.x, v.y);
      sS2t[n2 + 1][row] = make_float2(v.z, v.w);
    }
    // stage sCp [16 n][128 col]: 1024 float4, 4/thread
    #pragma unroll
    for (int it = 0; it < 4; ++it) {
      int e = tid + it * 256;
      int col2 = (e & 63) * 2;
      int n = e >> 6;                  // 0..15
      float4 v = *(const float4*)(Cp + (size_t)(kidx * 64 + nh * 16 + n) * MOUT + col2);
      *(float4*)&sCp[n][col2] = v;
    }
    __syncthreads();
    #pragma unroll 4
    for (int n = 0; n < 16; ++n) {
      float2 a[4];
      #pragma unroll
      for (int jj = 0; jj < 4; ++jj) a[jj] = sS2t[n][rg + jj * 16];
      float4 w[4];
      #pragma unroll
      for (int q = 0; q < 4; ++q) w[q] = *(const float4*)&sCp[n][c0 + q * 2];
      float cx[8] = {w[0].x, w[0].z, w[1].x, w[1].z, w[2].x, w[2].z, w[3].x, w[3].z};
      float cy[8] = {w[0].y, w[0].w, w[1].y, w[1].w, w[2].y, w[2].w, w[3].y, w[3].w};
      #pragma unroll
      for (int jj = 0; jj < 4; ++jj)
        #pragma unroll
        for (int q = 0; q < 8; ++q)
          acc[jj][q] = __fadd_rn(acc[jj][q],
              __fsub_rn(__fmul_rn(a[jj].x, cx[q]), __fmul_rn(a[jj].y, cy[q])));
    }
  }
  // epilogue: P[kidx][row][col] = (accn + xc*D) + Do
  float dv[8], ovv[8];
  *(float4*)&dv[0]  = *(const float4*)(D + kidx * MOUT + c0);
  *(float4*)&dv[4]  = *(const float4*)(D + kidx * MOUT + c0 + 4);
  *(float4*)&ovv[0] = *(const float4*)(Dov + c0);
  *(float4*)&ovv[4] = *(const float4*)(Dov + c0 + 4);
  #pragma unroll
  for (int jj = 0; jj < 4; ++jj) {
    int row = rowBase + rg + jj * 16;
    float xv = xcq[(size_t)(c * 4096 + row) * KP + kidx];
    float res[8];
    #pragma unroll
    for (int q = 0; q < 8; ++q)
      res[q] = __fadd_rn(__fadd_rn(acc[jj][q], __fmul_rn(xv, dv[q])), ovv[q]);
    float* pp = P + ((size_t)kidx * 4096 + row) * MOUT + c0;
    *(float4*)pp       = make_float4(res[0], res[1], res[2], res[3]);
    *(float4*)(pp + 4) = make_float4(res[4], res[5], res[6], res[7]);
  }
}

// ---------------------------------------------------------------------------
// out = (P0 + ... + P15)/16, k ascending (bit-matches rounds 4-6 msum).
__global__ __launch_bounds__(256) void k_combine(const float* __restrict__ P,
                     float* __restrict__ out, int c) {
  int idx = blockIdx.x * 256 + threadIdx.x;   // 131072 float4s
  int r  = idx >> 5;
  int m4 = (idx & 31) * 4;
  float4 s = *(const float4*)(P + (size_t)r * MOUT + m4);
  #pragma unroll
  for (int k = 1; k < KP; ++k) {
    float4 p = *(const float4*)(P + ((size_t)k * 4096 + r) * MOUT + m4);
    s.x = __fadd_rn(s.x, p.x);
    s.y = __fadd_rn(s.y, p.y);
    s.z = __fadd_rn(s.z, p.z);
    s.w = __fadd_rn(s.w, p.w);
  }
  int rg = c * 4096 + r;
  int t = rg >> 4, b = rg & 15;
  float4 res;
  res.x = __fdiv_rn(s.x, 16.0f);
  res.y = __fdiv_rn(s.y, 16.0f);
  res.z = __fdiv_rn(s.z, 16.0f);
  res.w = __fdiv_rn(s.w, 16.0f);
  *(float4*)(out + ((size_t)b * TLEN + t) * MOUT + m4) = res;
}

// ---------------------------------------------------------------------------
extern "C" void kernel_launch(void* const* d_in, const int* in_sizes, int n_in,
                              void* d_out, int out_size, void* d_ws, size_t ws_size,
                              hipStream_t stream) {
  const float* x     = (const float*)d_in[0];
  const float* R     = (const float*)d_in[1];
  const float* theta = (const float*)d_in[2];
  const float* C     = (const float*)d_in[3];
  const float* D     = (const float*)d_in[4];
  const float* Do    = (const float*)d_in[5];
  float* out = (float*)d_out;
  float* ws  = (float*)d_ws;
  float*  xcq = ws + XCQ_OFF;
  float2* lam = (float2*)(ws + LAM_OFF);
  float2* Bq  = (float2*)(ws + BQ_OFF);
  float2* Cp  = (float2*)(ws + CP_OFF);
  float*  st  = ws + ST_OFF;
  float2* S2  = (float2*)(ws + S2_OFF);
  float*  P   = ws + P_OFF;

  hipLaunchKernelGGL(k_lam_B, dim3(256),  dim3(256), 0, stream, theta, lam, Bq);
  hipLaunchKernelGGL(k_Cp,    dim3(1024), dim3(128), 0, stream, theta, C, Cp);
  hipLaunchKernelGGL(k_xc,    dim3(1024), dim3(256), 0, stream, x, R, xcq);
  for (int c = 0; c < NCHUNK; ++c) {
    hipLaunchKernelGGL(k_scan,    dim3(256),  dim3(64),  0, stream, lam, Bq, xcq, S2, st, c);
    hipLaunchKernelGGL(k_y,       dim3(1024), dim3(256), 0, stream, S2, Cp, xcq, D, Do, P, c);
    hipLaunchKernelGGL(k_combine, dim3(512),  dim3(256), 0, stream, P, out, c);
  }
}